// Round 11
// baseline (887.683 us; speedup 1.0000x reference)
//
#include <hip/hip_runtime.h>

#define LQN 21760
#define LVN 21760
#define BATCH 2
#define CDIM 256
#define HDN 8
#define DDIM 32
// padded per-(b,h) image: 130*130 + 66*66 + 34*34 + 18*18 = 22736 cells
#define PADCELLS 22736

typedef __attribute__((ext_vector_type(8))) short short8;
typedef __attribute__((ext_vector_type(4))) float f32x4;
typedef __attribute__((ext_vector_type(2))) float f32x2;

__device__ __forceinline__ unsigned short f2bf(float f) {
  union { float f; unsigned int u; } v; v.f = f;
  unsigned int r = v.u + 0x7fffu + ((v.u >> 16) & 1u);
  return (unsigned short)(r >> 16);
}
__device__ __forceinline__ float bflo(unsigned int u) {
  union { unsigned int u; float f; } v; v.u = u << 16; return v.f;
}
__device__ __forceinline__ float bfhi(unsigned int u) {
  union { unsigned int u; float f; } v; v.u = u & 0xffff0000u; return v.f;
}
// HW packed f32->bf16 (RNE), 2 values in 1 inst
__device__ __forceinline__ unsigned pk2bf(float lo, float hi) {
  unsigned r;
  asm("v_cvt_pk_bf16_f32 %0, %1, %2" : "=v"(r) : "v"(lo), "v"(hi));
  return r;
}

template <int IMM>
__device__ __forceinline__ float swzf(float v) {
  return __int_as_float(__builtin_amdgcn_ds_swizzle(__float_as_int(v), IMM));
}
template <int IMM>
__device__ __forceinline__ unsigned swzu(unsigned v) {
  return (unsigned)__builtin_amdgcn_ds_swizzle((int)v, IMM);
}

// -------- fused: weight transpose (blocks 0..383) + border zero (384..639) --
__global__ __launch_bounds__(256) void prep_zero_kernel(
    const float* __restrict__ Wval, const float* __restrict__ Woff,
    const float* __restrict__ Wattn, const float* __restrict__ Wout,
    unsigned short* __restrict__ wtval, unsigned short* __restrict__ wtoa,
    unsigned short* __restrict__ wtout, unsigned short* __restrict__ vbf) {
  const int b = blockIdx.x;
  if (b < 384) {
    const int idx = b * 256 + threadIdx.x;  // 0 .. 98303
    const int n = idx >> 8, k = idx & 255;
    if (idx < 65536) {
      wtval[idx] = f2bf(Wval[k * 256 + n]);
      wtout[idx] = f2bf(Wout[k * 256 + n]);
    }
    const float v = (n < 256) ? Woff[k * 256 + n] : Wattn[k * 128 + (n - 256)];
    wtoa[idx] = f2bf(v);
  } else {
    const int b2 = b - 384;
    const int img = b2 >> 4;                            // 0..15
    const int tid = (b2 & 15) * 256 + threadIdx.x;      // 0..4095
    const int cell = tid >> 2;
    const int chunk = tid & 3;
    if (cell >= 976) return;
    const int lvl = (cell >= 516) + (cell >= 776) + (cell >= 908);
    const int base = (lvl == 0) ? 0 : (lvl == 1) ? 516 : (lvl == 2) ? 776 : 908;
    const int W2 = (lvl == 0) ? 130 : (lvl == 1) ? 66 : (lvl == 2) ? 34 : 18;
    const int pst = (lvl == 0) ? 0 : (lvl == 1) ? 16900 : (lvl == 2) ? 21256 : 22412;
    const int bb = cell - base;
    int x, y;
    if (bb < W2) { y = 0; x = bb; }
    else if (bb < 2 * W2) { y = W2 - 1; x = bb - W2; }
    else { const int r = bb - 2 * W2; y = 1 + (r >> 1); x = (r & 1) ? (W2 - 1) : 0; }
    const size_t off = (((size_t)img * PADCELLS + pst + y * W2 + x) << 5) + chunk * 8;
    *(uint4*)(vbf + off) = (uint4){0u, 0u, 0u, 0u};
  }
}

// ------------- GEMM 128x128 tile body, double-buffered single-barrier -------
// MODE 0: A=value(f32) -> padded v_bf16[B,HD,PADCELLS,32] scatter (+b_val)
// MODE 1: A=query(f32) -> offattn bf16 [M,384] (+b_off/b_attn)
// MODE 2: A=msout(bf16) -> d_out f32 [M,256] (+b_out +query residual)
template <int MODE>
__device__ __forceinline__ void gemm_body(
    unsigned short* lsA0, unsigned short* lsB0, const int bx, const int by,
    const float* __restrict__ Af32, const unsigned short* __restrict__ Abf,
    const unsigned short* __restrict__ Wt, const float* __restrict__ bias0,
    const float* __restrict__ bias1, const float* __restrict__ resid,
    unsigned short* __restrict__ out_bf, float* __restrict__ out_f32) {
  constexpr int K = 256;
  constexpr int LDSS = 40;  // row stride (shorts): 80B
  constexpr int LBUF = 128 * LDSS;
  const int m0 = bx * 128;
  const int n0 = by * 128;
  const int t = threadIdx.x;
  const int w = t >> 6;
  const int l = t & 63;
  const int wr = (w >> 1) * 64;
  const int wc = (w & 1) * 64;
  const int fr = l & 15;
  const int kk = (l >> 4) * 8;

  f32x4 acc[4][4];
#pragma unroll
  for (int mi = 0; mi < 4; ++mi)
#pragma unroll
    for (int ci = 0; ci < 4; ++ci) acc[mi][ci] = (f32x4){0.f, 0.f, 0.f, 0.f};

  // staging maps: full-128B-line coverage per wave instruction
  const int ar8 = t >> 3, ak8 = (t & 7) * 4;   // f32 A: 8 lanes x 16B / row
  const int ar4 = t >> 2, ak4 = (t & 3) * 8;   // bf16 A/B: 4 lanes x 16B / row

  float4 fa[4];
  uint4 ua2[2];
  uint4 ub[2];

#define LOADA(kt)                                                            \
  do {                                                                       \
    const int k0_ = (kt) * 32;                                               \
    if (MODE == 2) {                                                         \
      ua2[0] = *(const uint4*)(Abf + (size_t)(m0 + ar4) * K + k0_ + ak4);    \
      ua2[1] = *(const uint4*)(Abf + (size_t)(m0 + 64 + ar4) * K + k0_ + ak4);\
    } else {                                                                 \
      fa[0] = *(const float4*)(Af32 + (size_t)(m0 + ar8) * K + k0_ + ak8);   \
      fa[1] = *(const float4*)(Af32 + (size_t)(m0 + 32 + ar8) * K + k0_ + ak8);\
      fa[2] = *(const float4*)(Af32 + (size_t)(m0 + 64 + ar8) * K + k0_ + ak8);\
      fa[3] = *(const float4*)(Af32 + (size_t)(m0 + 96 + ar8) * K + k0_ + ak8);\
    }                                                                        \
    ub[0] = *(const uint4*)(Wt + (size_t)(n0 + ar4) * K + k0_ + ak4);        \
    ub[1] = *(const uint4*)(Wt + (size_t)(n0 + 64 + ar4) * K + k0_ + ak4);   \
  } while (0)

#define STOREL(buf)                                                          \
  do {                                                                       \
    unsigned short* la = lsA0 + (buf)*LBUF;                                  \
    unsigned short* lb = lsB0 + (buf)*LBUF;                                  \
    if (MODE == 2) {                                                         \
      *(uint4*)(la + ar4 * LDSS + ak4) = ua2[0];                             \
      *(uint4*)(la + (64 + ar4) * LDSS + ak4) = ua2[1];                      \
    } else {                                                                 \
      uint2 q;                                                               \
      q.x = pk2bf(fa[0].x, fa[0].y); q.y = pk2bf(fa[0].z, fa[0].w);          \
      *(uint2*)(la + ar8 * LDSS + ak8) = q;                                  \
      q.x = pk2bf(fa[1].x, fa[1].y); q.y = pk2bf(fa[1].z, fa[1].w);          \
      *(uint2*)(la + (32 + ar8) * LDSS + ak8) = q;                           \
      q.x = pk2bf(fa[2].x, fa[2].y); q.y = pk2bf(fa[2].z, fa[2].w);          \
      *(uint2*)(la + (64 + ar8) * LDSS + ak8) = q;                           \
      q.x = pk2bf(fa[3].x, fa[3].y); q.y = pk2bf(fa[3].z, fa[3].w);          \
      *(uint2*)(la + (96 + ar8) * LDSS + ak8) = q;                           \
    }                                                                        \
    *(uint4*)(lb + ar4 * LDSS + ak4) = ub[0];                                \
    *(uint4*)(lb + (64 + ar4) * LDSS + ak4) = ub[1];                         \
  } while (0)

  LOADA(0);
  STOREL(0);
  __syncthreads();

#pragma unroll
  for (int kt = 0; kt < 8; ++kt) {
    if (kt < 7) LOADA(kt + 1);
    const unsigned short* la = lsA0 + (kt & 1) * LBUF;
    const unsigned short* lb = lsB0 + (kt & 1) * LBUF;
    short8 af[4], bfr[4];
#pragma unroll
    for (int mi = 0; mi < 4; ++mi)
      af[mi] = *(const short8*)(la + (wr + mi * 16 + fr) * LDSS + kk);
#pragma unroll
    for (int ci = 0; ci < 4; ++ci)
      bfr[ci] = *(const short8*)(lb + (wc + ci * 16 + fr) * LDSS + kk);
#pragma unroll
    for (int mi = 0; mi < 4; ++mi)
#pragma unroll
      for (int ci = 0; ci < 4; ++ci)
        acc[mi][ci] = __builtin_amdgcn_mfma_f32_16x16x32_bf16(
            af[mi], bfr[ci], acc[mi][ci], 0, 0, 0);
    if (kt < 7) STOREL((kt + 1) & 1);
    __syncthreads();
  }
#undef LOADA
#undef STOREL

  const int fq = l >> 4;
  if (MODE == 0) {
    int rbase[16];
#pragma unroll
    for (int mi = 0; mi < 4; ++mi) {
#pragma unroll
      for (int r = 0; r < 4; ++r) {
        const int row = m0 + wr + mi * 16 + fq * 4 + r;
        const int bb = (row >= LVN) ? 1 : 0;
        const int i = row - bb * LVN;
        const int lvl = (i >= 16384) + (i >= 20480) + (i >= 21504);
        const int stl = (lvl == 0) ? 0 : (lvl == 1) ? 16384 : (lvl == 2) ? 20480 : 21504;
        const int pst = (lvl == 0) ? 0 : (lvl == 1) ? 16900 : (lvl == 2) ? 21256 : 22412;
        const int lw = 7 - lvl;
        const int Wl = 128 >> lvl;
        const int loc = i - stl;
        const int y = loc >> lw;
        const int x = loc & (Wl - 1);
        const int pidx = pst + (y + 1) * (Wl + 2) + (x + 1);
        rbase[mi * 4 + r] = bb * (HDN * PADCELLS * DDIM) + pidx * DDIM;
      }
    }
#pragma unroll
    for (int ci = 0; ci < 4; ++ci) {
      const int col = n0 + wc + ci * 16 + fr;
      const float bias = bias0[col];
      const int cterm = (col >> 5) * (PADCELLS * DDIM) + (col & 31);
#pragma unroll
      for (int mi = 0; mi < 4; ++mi) {
#pragma unroll
        for (int r = 0; r < 4; r += 2) {
          const unsigned u =
              pk2bf(acc[mi][ci][r] + bias, acc[mi][ci][r + 1] + bias);
          out_bf[(size_t)(rbase[mi * 4 + r] + cterm)] = (unsigned short)u;
          out_bf[(size_t)(rbase[mi * 4 + r + 1] + cterm)] =
              (unsigned short)(u >> 16);
        }
      }
    }
  } else if (MODE == 1) {
#pragma unroll
    for (int ci = 0; ci < 4; ++ci) {
      const int col = n0 + wc + ci * 16 + fr;
      const float bias = (col < 256) ? bias0[col] : bias1[col - 256];
#pragma unroll
      for (int mi = 0; mi < 4; ++mi) {
        const int row0 = m0 + wr + mi * 16 + fq * 4;
#pragma unroll
        for (int r = 0; r < 4; r += 2) {
          const unsigned u =
              pk2bf(acc[mi][ci][r] + bias, acc[mi][ci][r + 1] + bias);
          out_bf[(size_t)(row0 + r) * 384 + col] = (unsigned short)u;
          out_bf[(size_t)(row0 + r + 1) * 384 + col] = (unsigned short)(u >> 16);
        }
      }
    }
  } else {
#pragma unroll
    for (int ci = 0; ci < 4; ++ci) {
      const int col = n0 + wc + ci * 16 + fr;
      const float bias = bias0[col];
#pragma unroll
      for (int mi = 0; mi < 4; ++mi) {
#pragma unroll
        for (int r = 0; r < 4; ++r) {
          const int row = m0 + wr + mi * 16 + fq * 4 + r;
          const size_t o = (size_t)row * 256 + col;
          out_f32[o] = acc[mi][ci][r] + bias + resid[o];
        }
      }
    }
  }
}

// -------- fused GEMM0+GEMM1; XCD-aligned A-panel sharing --------------------
__global__ __launch_bounds__(256) void gemm01_kernel(
    const float* __restrict__ value, const float* __restrict__ query,
    const unsigned short* __restrict__ wtval,
    const unsigned short* __restrict__ wtoa, const float* __restrict__ b_val,
    const float* __restrict__ b_off, const float* __restrict__ b_attn,
    unsigned short* __restrict__ vbf, unsigned short* __restrict__ offattn) {
  const int bid = blockIdx.x;  // 0..1719
  const int q = bid / 40;
  const int rem = bid % 40;
  const int g = rem >> 3;      // 0..4
  const int r = rem & 7;
  const int u = q * 8 + r;     // A-panel index; same u -> same XCD
  if (u >= 340) return;
  __shared__ unsigned short lsA[2 * 128 * 40];
  __shared__ unsigned short lsB[2 * 128 * 40];
  if (g < 2) {
    gemm_body<0>(lsA, lsB, u, g, value, nullptr, wtval, b_val, nullptr,
                 nullptr, vbf, nullptr);
  } else {
    gemm_body<1>(lsA, lsB, u, g - 2, query, nullptr, wtoa, b_off, b_attn,
                 nullptr, offattn, nullptr);
  }
}

// -------- GEMM2 (msout -> out, +bias +residual), XCD-aligned msout panel ----
__global__ __launch_bounds__(256) void gemm2_kernel(
    const unsigned short* __restrict__ msout,
    const unsigned short* __restrict__ wtout, const float* __restrict__ b_out,
    const float* __restrict__ query, float* __restrict__ out) {
  const int bid = blockIdx.x;  // 0..687
  const int q = bid / 16;
  const int rem = bid % 16;
  const int y = rem >> 3;
  const int r = rem & 7;
  const int u = q * 8 + r;
  if (u >= 340) return;
  __shared__ unsigned short lsA[2 * 128 * 40];
  __shared__ unsigned short lsB[2 * 128 * 40];
  gemm_body<2>(lsA, lsB, u, y, nullptr, msout, wtout, b_out, nullptr, query,
               nullptr, out);
}

// --- sampler: 512 thr = 128 q x ONE image (XCD-pinned); owner-lane de-dup; --
// --- level 3 staged in LDS (324 padded cells, 80B stride, bank-spread) ------
__global__ __launch_bounds__(512) void sampler_kernel(
    const unsigned short* __restrict__ vbf,      // padded [B,HD,PADCELLS,32]
    const unsigned short* __restrict__ offattn,  // [B*LQ,384] bf16
    const float* __restrict__ refpts,            // [B,LQ,4,2] f32
    unsigned short* __restrict__ msout) {        // [B*LQ,256] bf16
  __shared__ unsigned short slds[324 * 40];  // 25,920 B

  const int lid = blockIdx.x;            // 0 .. 2719
  const int pair = lid & 7;              // image pair -> XCD (empirical %8)
  const int k = lid >> 3;                // 0 .. 339
  const int img = pair * 2 + (k & 1);    // 0 .. 15  (= bb*8 + h)
  const int qchunk = k >> 1;             // 0 .. 169
  const int h = img & 7;
  const int bb = img >> 3;

  const int t = threadIdx.x;             // 0..511
  const int lane = t & 63;
  const int qloc = qchunk * 128 + (t >> 6) * 16 + (lane >> 2);
  const int qi = bb * LQN + qloc;
  const int j = lane & 3;  // dim-quad id AND owned level
  const int d0 = j * 8;
  const int jj8 = j * 8;   // LDS chunk offset (shorts)

  const size_t imgbase = (size_t)img * (PADCELLS * DDIM);

  // ---- issue level-3 stage loads early (1296 uint4 over 512 threads) ----
  const unsigned short* l3src = vbf + imgbase + 22412 * 32;
  uint4 s0, s1, s2;
  s0 = *(const uint4*)(l3src + (size_t)t * 8);
  s1 = *(const uint4*)(l3src + (size_t)(t + 512) * 8);
  const bool has3 = (t < 272);
  if (has3) s2 = *(const uint4*)(l3src + (size_t)(t + 1024) * 8);

  const unsigned short* oa = offattn + (size_t)qi * 384;

  // ---- owner geometry (level j); j==3 emits LDS cell indices ----
  const int Wl = 128 >> j;
  const int W2 = Wl + 2;
  const unsigned obase =
      (j == 0) ? 0u : (j == 1) ? 16900u : (j == 2) ? 21256u : 0u;
  const int oshift = (j == 3) ? 0 : 5;
  const float fw = (float)Wl;

  // ---- distributed softmax: lane owns logits [4j, 4j+4) ----
  const uint2 lr = *(const uint2*)(oa + 256 + h * 16 + j * 4);
  const float l0 = bflo(lr.x), l1 = bfhi(lr.x);
  const float l2 = bflo(lr.y), l3 = bfhi(lr.y);
  float mx = fmaxf(fmaxf(l0, l1), fmaxf(l2, l3));
  mx = fmaxf(mx, swzf<0x041F>(mx));  // xor 1 (within quad)
  mx = fmaxf(mx, swzf<0x081F>(mx));  // xor 2
  const float e0v = __expf(l0 - mx), e1v = __expf(l1 - mx);
  const float e2v = __expf(l2 - mx), e3v = __expf(l3 - mx);
  float s = (e0v + e1v) + (e2v + e3v);
  s += swzf<0x041F>(s);
  s += swzf<0x081F>(s);
  const float inv = 1.f / s;
  const float aw4[4] = {e0v * inv, e1v * inv, e2v * inv, e3v * inv};

  const float2 rf = *(const float2*)(refpts + (size_t)qi * 8 + j * 2);
  const uint4 ov = *(const uint4*)(oa + h * 32 + j * 8);
  const unsigned op_[4] = {ov.x, ov.y, ov.z, ov.w};

  // ---- owner per-point math: 4 corner offsets (elem or cell) + 4 weights --
  unsigned eo[4][4];
  float wt[4][4];
#pragma unroll
  for (int pt = 0; pt < 4; ++pt) {
    const float ox = bflo(op_[pt]);
    const float oy = bfhi(op_[pt]);
    const float xs = fmaf(rf.x, fw, ox) - 0.5f;
    const float ys = fmaf(rf.y, fw, oy) - 0.5f;
    const float x0f = floorf(xs), y0f = floorf(ys);
    const float lx = xs - x0f, ly = ys - y0f;
    const int x0 = (int)x0f, y0 = (int)y0f;
    const float a = aw4[pt];
    const float wy1 = a * ly, wy0 = a - wy1;
    const float w01v = wy0 * lx, w00v = wy0 - w01v;
    const float w11v = wy1 * lx, w10v = wy1 - w11v;
    const int xb0 = min(max(x0 + 1, 0), Wl + 1);
    const int xb1 = min(max(x0 + 2, 0), Wl + 1);
    const int yb0 = min(max(y0 + 1, 0), Wl + 1);
    const int yb1 = min(max(y0 + 2, 0), Wl + 1);
    const unsigned r0 = obase + (unsigned)(yb0 * W2);
    const unsigned r1 = obase + (unsigned)(yb1 * W2);
    eo[pt][0] = (r0 + xb0) << oshift;
    eo[pt][1] = (r0 + xb1) << oshift;
    eo[pt][2] = (r1 + xb0) << oshift;
    eo[pt][3] = (r1 + xb1) << oshift;
    wt[pt][0] = w00v; wt[pt][1] = w01v; wt[pt][2] = w10v; wt[pt][3] = w11v;
  }

  const unsigned short* vb = vbf + imgbase + d0;

  f32x2 acc0 = (f32x2){0.f, 0.f}, acc1 = (f32x2){0.f, 0.f};
  f32x2 acc2 = (f32x2){0.f, 0.f}, acc3 = (f32x2){0.f, 0.f};

#define ACCUM(rv, wgt)                                 \
  {                                                    \
    f32x2 v_;                                          \
    v_.x = bflo(rv.x); v_.y = bfhi(rv.x);              \
    acc0 += v_ * (wgt);                                \
    v_.x = bflo(rv.y); v_.y = bfhi(rv.y);              \
    acc1 += v_ * (wgt);                                \
    v_.x = bflo(rv.z); v_.y = bfhi(rv.z);              \
    acc2 += v_ * (wgt);                                \
    v_.x = bflo(rv.w); v_.y = bfhi(rv.w);              \
    acc3 += v_ * (wgt);                                \
  }

// global gather: quad-broadcast from quad-lane LVL (and=0x1C, or=LVL)
#define POINT(LVL, PT)                                                  \
  {                                                                     \
    constexpr int IMM = (LVL << 5) | 0x1C;                              \
    const unsigned o00 = swzu<IMM>(eo[PT][0]);                          \
    const unsigned o01 = swzu<IMM>(eo[PT][1]);                          \
    const unsigned o10 = swzu<IMM>(eo[PT][2]);                          \
    const unsigned o11 = swzu<IMM>(eo[PT][3]);                          \
    const float w00 = swzf<IMM>(wt[PT][0]);                             \
    const float w01 = swzf<IMM>(wt[PT][1]);                             \
    const float w10 = swzf<IMM>(wt[PT][2]);                             \
    const float w11 = swzf<IMM>(wt[PT][3]);                             \
    const uint4 v00 = *(const uint4*)(vb + o00);                        \
    const uint4 v01 = *(const uint4*)(vb + o01);                        \
    const uint4 v10 = *(const uint4*)(vb + o10);                        \
    const uint4 v11 = *(const uint4*)(vb + o11);                        \
    ACCUM(v00, w00)                                                     \
    ACCUM(v01, w01)                                                     \
    ACCUM(v10, w10)                                                     \
    ACCUM(v11, w11)                                                     \
  }

// LDS gather for level 3: broadcast cell index from quad-lane 3
#define POINTL(PT)                                                      \
  {                                                                     \
    constexpr int IMM = (3 << 5) | 0x1C;                                \
    const unsigned c00 = swzu<IMM>(eo[PT][0]);                          \
    const unsigned c01 = swzu<IMM>(eo[PT][1]);                          \
    const unsigned c10 = swzu<IMM>(eo[PT][2]);                          \
    const unsigned c11 = swzu<IMM>(eo[PT][3]);                          \
    const float w00 = swzf<IMM>(wt[PT][0]);                             \
    const float w01 = swzf<IMM>(wt[PT][1]);                             \
    const float w10 = swzf<IMM>(wt[PT][2]);                             \
    const float w11 = swzf<IMM>(wt[PT][3]);                             \
    const uint4 v00 = *(const uint4*)(slds + c00 * 40 + jj8);           \
    const uint4 v01 = *(const uint4*)(slds + c01 * 40 + jj8);           \
    const uint4 v10 = *(const uint4*)(slds + c10 * 40 + jj8);           \
    const uint4 v11 = *(const uint4*)(slds + c11 * 40 + jj8);           \
    ACCUM(v00, w00)                                                     \
    ACCUM(v01, w01)                                                     \
    ACCUM(v10, w10)                                                     \
    ACCUM(v11, w11)                                                     \
  }

  // levels 0..2 from global while the stage loads are in flight
  POINT(0, 0) POINT(0, 1) POINT(0, 2) POINT(0, 3)
  POINT(1, 0) POINT(1, 1) POINT(1, 2) POINT(1, 3)
  POINT(2, 0) POINT(2, 1) POINT(2, 2) POINT(2, 3)

  // commit stage to LDS (compiler inserts vmcnt wait here), then barrier
  {
    const int f0 = t;
    *(uint4*)(slds + (f0 >> 2) * 40 + (f0 & 3) * 8) = s0;
    const int f1 = t + 512;
    *(uint4*)(slds + (f1 >> 2) * 40 + (f1 & 3) * 8) = s1;
    if (has3) {
      const int f2 = t + 1024;
      *(uint4*)(slds + (f2 >> 2) * 40 + (f2 & 3) * 8) = s2;
    }
  }
  __syncthreads();

  POINTL(0) POINTL(1) POINTL(2) POINTL(3)
#undef POINT
#undef POINTL
#undef ACCUM

  uint4 outv;
  outv.x = pk2bf(acc0.x, acc0.y);
  outv.y = pk2bf(acc1.x, acc1.y);
  outv.z = pk2bf(acc2.x, acc2.y);
  outv.w = pk2bf(acc3.x, acc3.y);
  *(uint4*)(msout + (size_t)qi * 256 + h * 32 + d0) = outv;
}

// ---------------- launch ----------------------------------------------------
extern "C" void kernel_launch(void* const* d_in, const int* in_sizes, int n_in,
                              void* d_out, int out_size, void* d_ws,
                              size_t ws_size, hipStream_t stream) {
  const float* query = (const float*)d_in[0];
  const float* refpts = (const float*)d_in[1];
  const float* value = (const float*)d_in[2];
  const float* W_off = (const float*)d_in[5];
  const float* b_off = (const float*)d_in[6];
  const float* W_attn = (const float*)d_in[7];
  const float* b_attn = (const float*)d_in[8];
  const float* W_val = (const float*)d_in[9];
  const float* b_val = (const float*)d_in[10];
  const float* W_out = (const float*)d_in[11];
  const float* b_out = (const float*)d_in[12];
  float* out = (float*)d_out;

  char* ws = (char*)d_ws;
  unsigned short* wtval = (unsigned short*)(ws);                 // 131072 B
  unsigned short* wtoa = (unsigned short*)(ws + 131072);         // 196608 B
  unsigned short* wtout = (unsigned short*)(ws + 327680);        // 131072 B
  unsigned short* vbf = (unsigned short*)(ws + 458752);          // 23281664 B
  unsigned short* offattn = (unsigned short*)(ws + 23740416);    // 33423360 B
  unsigned short* msout = (unsigned short*)(ws + 57163776);      // 22282240 B

  prep_zero_kernel<<<640, 256, 0, stream>>>(W_val, W_off, W_attn, W_out, wtval,
                                            wtoa, wtout, vbf);
  gemm01_kernel<<<1720, 256, 0, stream>>>(value, query, wtval, wtoa, b_val,
                                          b_off, b_attn, vbf, offattn);
  sampler_kernel<<<2720, 512, 0, stream>>>(vbf, offattn, refpts, msout);
  gemm2_kernel<<<688, 256, 0, stream>>>(msout, wtout, b_out, query, out);
}

// Round 12
// 150.110 us; speedup vs baseline: 5.9135x; 5.9135x over previous
//
#include <hip/hip_runtime.h>

#define LQN 21760
#define LVN 21760
#define BATCH 2
#define CDIM 256
#define HDN 8
#define DDIM 32
// padded per-(b,h) image: 130*130 + 66*66 + 34*34 + 18*18 = 22736 cells
#define PADCELLS 22736

typedef __attribute__((ext_vector_type(8))) short short8;
typedef __attribute__((ext_vector_type(4))) float f32x4;
typedef __attribute__((ext_vector_type(2))) float f32x2;

__device__ __forceinline__ unsigned short f2bf(float f) {
  union { float f; unsigned int u; } v; v.f = f;
  unsigned int r = v.u + 0x7fffu + ((v.u >> 16) & 1u);
  return (unsigned short)(r >> 16);
}
__device__ __forceinline__ float bflo(unsigned int u) {
  union { unsigned int u; float f; } v; v.u = u << 16; return v.f;
}
__device__ __forceinline__ float bfhi(unsigned int u) {
  union { unsigned int u; float f; } v; v.u = u & 0xffff0000u; return v.f;
}
// HW packed f32->bf16 (RNE), 2 values in 1 inst
__device__ __forceinline__ unsigned pk2bf(float lo, float hi) {
  unsigned r;
  asm("v_cvt_pk_bf16_f32 %0, %1, %2" : "=v"(r) : "v"(lo), "v"(hi));
  return r;
}

template <int IMM>
__device__ __forceinline__ float swzf(float v) {
  return __int_as_float(__builtin_amdgcn_ds_swizzle(__float_as_int(v), IMM));
}
template <int IMM>
__device__ __forceinline__ unsigned swzu(unsigned v) {
  return (unsigned)__builtin_amdgcn_ds_swizzle((int)v, IMM);
}

// -------- fused: weight transpose (blocks 0..383) + border zero (384..639) --
__global__ __launch_bounds__(256) void prep_zero_kernel(
    const float* __restrict__ Wval, const float* __restrict__ Woff,
    const float* __restrict__ Wattn, const float* __restrict__ Wout,
    unsigned short* __restrict__ wtval, unsigned short* __restrict__ wtoa,
    unsigned short* __restrict__ wtout, unsigned short* __restrict__ vbf) {
  const int b = blockIdx.x;
  if (b < 384) {
    const int idx = b * 256 + threadIdx.x;  // 0 .. 98303
    const int n = idx >> 8, k = idx & 255;
    if (idx < 65536) {
      wtval[idx] = f2bf(Wval[k * 256 + n]);
      wtout[idx] = f2bf(Wout[k * 256 + n]);
    }
    const float v = (n < 256) ? Woff[k * 256 + n] : Wattn[k * 128 + (n - 256)];
    wtoa[idx] = f2bf(v);
  } else {
    const int b2 = b - 384;
    const int img = b2 >> 4;                            // 0..15
    const int tid = (b2 & 15) * 256 + threadIdx.x;      // 0..4095
    const int cell = tid >> 2;
    const int chunk = tid & 3;
    if (cell >= 976) return;
    const int lvl = (cell >= 516) + (cell >= 776) + (cell >= 908);
    const int base = (lvl == 0) ? 0 : (lvl == 1) ? 516 : (lvl == 2) ? 776 : 908;
    const int W2 = (lvl == 0) ? 130 : (lvl == 1) ? 66 : (lvl == 2) ? 34 : 18;
    const int pst = (lvl == 0) ? 0 : (lvl == 1) ? 16900 : (lvl == 2) ? 21256 : 22412;
    const int bb = cell - base;
    int x, y;
    if (bb < W2) { y = 0; x = bb; }
    else if (bb < 2 * W2) { y = W2 - 1; x = bb - W2; }
    else { const int r = bb - 2 * W2; y = 1 + (r >> 1); x = (r & 1) ? (W2 - 1) : 0; }
    const size_t off = (((size_t)img * PADCELLS + pst + y * W2 + x) << 5) + chunk * 8;
    *(uint4*)(vbf + off) = (uint4){0u, 0u, 0u, 0u};
  }
}

// ------------- GEMM 128x128 tile body, double-buffered single-barrier -------
// MODE 0: A=value(f32) -> padded v_bf16[B,HD,PADCELLS,32] scatter (+b_val)
// MODE 1: A=query(f32) -> offattn bf16 [M,384] (+b_off/b_attn)
// MODE 2: A=msout(bf16) -> d_out f32 [M,256] (+b_out +query residual)
template <int MODE>
__device__ __forceinline__ void gemm_body(
    unsigned short* lsA0, unsigned short* lsB0, const int bx, const int by,
    const float* __restrict__ Af32, const unsigned short* __restrict__ Abf,
    const unsigned short* __restrict__ Wt, const float* __restrict__ bias0,
    const float* __restrict__ bias1, const float* __restrict__ resid,
    unsigned short* __restrict__ out_bf, float* __restrict__ out_f32) {
  constexpr int K = 256;
  constexpr int LDSS = 40;  // row stride (shorts): 80B
  constexpr int LBUF = 128 * LDSS;
  const int m0 = bx * 128;
  const int n0 = by * 128;
  const int t = threadIdx.x;
  const int w = t >> 6;
  const int l = t & 63;
  const int wr = (w >> 1) * 64;
  const int wc = (w & 1) * 64;
  const int fr = l & 15;
  const int kk = (l >> 4) * 8;

  f32x4 acc[4][4];
#pragma unroll
  for (int mi = 0; mi < 4; ++mi)
#pragma unroll
    for (int ci = 0; ci < 4; ++ci) acc[mi][ci] = (f32x4){0.f, 0.f, 0.f, 0.f};

  // staging maps: full-128B-line coverage per wave instruction
  const int ar8 = t >> 3, ak8 = (t & 7) * 4;   // f32 A: 8 lanes x 16B / row
  const int ar4 = t >> 2, ak4 = (t & 3) * 8;   // bf16 A/B: 4 lanes x 16B / row

  float4 fa[4];
  uint4 ua2[2];
  uint4 ub[2];

#define LOADA(kt)                                                            \
  do {                                                                       \
    const int k0_ = (kt) * 32;                                               \
    if (MODE == 2) {                                                         \
      ua2[0] = *(const uint4*)(Abf + (size_t)(m0 + ar4) * K + k0_ + ak4);    \
      ua2[1] = *(const uint4*)(Abf + (size_t)(m0 + 64 + ar4) * K + k0_ + ak4);\
    } else {                                                                 \
      fa[0] = *(const float4*)(Af32 + (size_t)(m0 + ar8) * K + k0_ + ak8);   \
      fa[1] = *(const float4*)(Af32 + (size_t)(m0 + 32 + ar8) * K + k0_ + ak8);\
      fa[2] = *(const float4*)(Af32 + (size_t)(m0 + 64 + ar8) * K + k0_ + ak8);\
      fa[3] = *(const float4*)(Af32 + (size_t)(m0 + 96 + ar8) * K + k0_ + ak8);\
    }                                                                        \
    ub[0] = *(const uint4*)(Wt + (size_t)(n0 + ar4) * K + k0_ + ak4);        \
    ub[1] = *(const uint4*)(Wt + (size_t)(n0 + 64 + ar4) * K + k0_ + ak4);   \
  } while (0)

#define STOREL(buf)                                                          \
  do {                                                                       \
    unsigned short* la = lsA0 + (buf)*LBUF;                                  \
    unsigned short* lb = lsB0 + (buf)*LBUF;                                  \
    if (MODE == 2) {                                                         \
      *(uint4*)(la + ar4 * LDSS + ak4) = ua2[0];                             \
      *(uint4*)(la + (64 + ar4) * LDSS + ak4) = ua2[1];                      \
    } else {                                                                 \
      uint2 q;                                                               \
      q.x = pk2bf(fa[0].x, fa[0].y); q.y = pk2bf(fa[0].z, fa[0].w);          \
      *(uint2*)(la + ar8 * LDSS + ak8) = q;                                  \
      q.x = pk2bf(fa[1].x, fa[1].y); q.y = pk2bf(fa[1].z, fa[1].w);          \
      *(uint2*)(la + (32 + ar8) * LDSS + ak8) = q;                           \
      q.x = pk2bf(fa[2].x, fa[2].y); q.y = pk2bf(fa[2].z, fa[2].w);          \
      *(uint2*)(la + (64 + ar8) * LDSS + ak8) = q;                           \
      q.x = pk2bf(fa[3].x, fa[3].y); q.y = pk2bf(fa[3].z, fa[3].w);          \
      *(uint2*)(la + (96 + ar8) * LDSS + ak8) = q;                           \
    }                                                                        \
    *(uint4*)(lb + ar4 * LDSS + ak4) = ub[0];                                \
    *(uint4*)(lb + (64 + ar4) * LDSS + ak4) = ub[1];                         \
  } while (0)

  LOADA(0);
  STOREL(0);
  __syncthreads();

#pragma unroll
  for (int kt = 0; kt < 8; ++kt) {
    if (kt < 7) LOADA(kt + 1);
    const unsigned short* la = lsA0 + (kt & 1) * LBUF;
    const unsigned short* lb = lsB0 + (kt & 1) * LBUF;
    short8 af[4], bfr[4];
#pragma unroll
    for (int mi = 0; mi < 4; ++mi)
      af[mi] = *(const short8*)(la + (wr + mi * 16 + fr) * LDSS + kk);
#pragma unroll
    for (int ci = 0; ci < 4; ++ci)
      bfr[ci] = *(const short8*)(lb + (wc + ci * 16 + fr) * LDSS + kk);
#pragma unroll
    for (int mi = 0; mi < 4; ++mi)
#pragma unroll
      for (int ci = 0; ci < 4; ++ci)
        acc[mi][ci] = __builtin_amdgcn_mfma_f32_16x16x32_bf16(
            af[mi], bfr[ci], acc[mi][ci], 0, 0, 0);
    if (kt < 7) STOREL((kt + 1) & 1);
    __syncthreads();
  }
#undef LOADA
#undef STOREL

  const int fq = l >> 4;
  if (MODE == 0) {
    int rbase[16];
#pragma unroll
    for (int mi = 0; mi < 4; ++mi) {
#pragma unroll
      for (int r = 0; r < 4; ++r) {
        const int row = m0 + wr + mi * 16 + fq * 4 + r;
        const int bb = (row >= LVN) ? 1 : 0;
        const int i = row - bb * LVN;
        const int lvl = (i >= 16384) + (i >= 20480) + (i >= 21504);
        const int stl = (lvl == 0) ? 0 : (lvl == 1) ? 16384 : (lvl == 2) ? 20480 : 21504;
        const int pst = (lvl == 0) ? 0 : (lvl == 1) ? 16900 : (lvl == 2) ? 21256 : 22412;
        const int lw = 7 - lvl;
        const int Wl = 128 >> lvl;
        const int loc = i - stl;
        const int y = loc >> lw;
        const int x = loc & (Wl - 1);
        const int pidx = pst + (y + 1) * (Wl + 2) + (x + 1);
        rbase[mi * 4 + r] = bb * (HDN * PADCELLS * DDIM) + pidx * DDIM;
      }
    }
#pragma unroll
    for (int ci = 0; ci < 4; ++ci) {
      const int col = n0 + wc + ci * 16 + fr;
      const float bias = bias0[col];
      const int cterm = (col >> 5) * (PADCELLS * DDIM) + (col & 31);
#pragma unroll
      for (int mi = 0; mi < 4; ++mi) {
#pragma unroll
        for (int r = 0; r < 4; r += 2) {
          const unsigned u =
              pk2bf(acc[mi][ci][r] + bias, acc[mi][ci][r + 1] + bias);
          out_bf[(size_t)(rbase[mi * 4 + r] + cterm)] = (unsigned short)u;
          out_bf[(size_t)(rbase[mi * 4 + r + 1] + cterm)] =
              (unsigned short)(u >> 16);
        }
      }
    }
  } else if (MODE == 1) {
#pragma unroll
    for (int ci = 0; ci < 4; ++ci) {
      const int col = n0 + wc + ci * 16 + fr;
      const float bias = (col < 256) ? bias0[col] : bias1[col - 256];
#pragma unroll
      for (int mi = 0; mi < 4; ++mi) {
        const int row0 = m0 + wr + mi * 16 + fq * 4;
#pragma unroll
        for (int r = 0; r < 4; r += 2) {
          const unsigned u =
              pk2bf(acc[mi][ci][r] + bias, acc[mi][ci][r + 1] + bias);
          out_bf[(size_t)(row0 + r) * 384 + col] = (unsigned short)u;
          out_bf[(size_t)(row0 + r + 1) * 384 + col] = (unsigned short)(u >> 16);
        }
      }
    }
  } else {
#pragma unroll
    for (int ci = 0; ci < 4; ++ci) {
      const int col = n0 + wc + ci * 16 + fr;
      const float bias = bias0[col];
#pragma unroll
      for (int mi = 0; mi < 4; ++mi) {
#pragma unroll
        for (int r = 0; r < 4; ++r) {
          const int row = m0 + wr + mi * 16 + fq * 4 + r;
          const size_t o = (size_t)row * 256 + col;
          out_f32[o] = acc[mi][ci][r] + bias + resid[o];
        }
      }
    }
  }
}

// -------- fused GEMM0+GEMM1; XCD-aligned A-panel sharing --------------------
__global__ __launch_bounds__(256) void gemm01_kernel(
    const float* __restrict__ value, const float* __restrict__ query,
    const unsigned short* __restrict__ wtval,
    const unsigned short* __restrict__ wtoa, const float* __restrict__ b_val,
    const float* __restrict__ b_off, const float* __restrict__ b_attn,
    unsigned short* __restrict__ vbf, unsigned short* __restrict__ offattn) {
  const int bid = blockIdx.x;  // 0..1719
  const int q = bid / 40;
  const int rem = bid % 40;
  const int g = rem >> 3;      // 0..4
  const int r = rem & 7;
  const int u = q * 8 + r;     // A-panel index; same u -> same XCD
  if (u >= 340) return;
  __shared__ unsigned short lsA[2 * 128 * 40];
  __shared__ unsigned short lsB[2 * 128 * 40];
  if (g < 2) {
    gemm_body<0>(lsA, lsB, u, g, value, nullptr, wtval, b_val, nullptr,
                 nullptr, vbf, nullptr);
  } else {
    gemm_body<1>(lsA, lsB, u, g - 2, query, nullptr, wtoa, b_off, b_attn,
                 nullptr, offattn, nullptr);
  }
}

// -------- GEMM2 (msout -> out, +bias +residual), XCD-aligned msout panel ----
__global__ __launch_bounds__(256) void gemm2_kernel(
    const unsigned short* __restrict__ msout,
    const unsigned short* __restrict__ wtout, const float* __restrict__ b_out,
    const float* __restrict__ query, float* __restrict__ out) {
  const int bid = blockIdx.x;  // 0..687
  const int q = bid / 16;
  const int rem = bid % 16;
  const int y = rem >> 3;
  const int r = rem & 7;
  const int u = q * 8 + r;
  if (u >= 340) return;
  __shared__ unsigned short lsA[2 * 128 * 40];
  __shared__ unsigned short lsB[2 * 128 * 40];
  gemm_body<2>(lsA, lsB, u, y, nullptr, msout, wtout, b_out, nullptr, query,
               nullptr, out);
}

// --- sampler: block = 64 q x ONE image (XCD-pinned); owner-lane de-dup -----
// wave = 16 queries x 4 lanes; quad-lane j owns level j's softmax slice,
// coords, weights, addresses; broadcast via quad ds_swizzle. (R8 verbatim.)
__global__ __launch_bounds__(256) void sampler_kernel(
    const unsigned short* __restrict__ vbf,      // padded [B,HD,PADCELLS,32]
    const unsigned short* __restrict__ offattn,  // [B*LQ,384] bf16
    const float* __restrict__ refpts,            // [B,LQ,4,2] f32
    unsigned short* __restrict__ msout) {        // [B*LQ,256] bf16
  const int lid = blockIdx.x;            // 0 .. 5439
  const int pair = lid & 7;              // image pair -> XCD (empirical %8)
  const int k = lid >> 3;                // 0 .. 679
  const int img = pair * 2 + (k & 1);    // 0 .. 15  (= bb*8 + h)
  const int qchunk = k >> 1;             // 0 .. 339
  const int h = img & 7;
  const int bb = img >> 3;

  const int t = threadIdx.x;
  const int lane = t & 63;
  const int qloc = qchunk * 64 + (t >> 6) * 16 + (lane >> 2);
  const int qi = bb * LQN + qloc;
  const int j = lane & 3;  // dim-quad id AND owned level
  const int d0 = j * 8;

  const unsigned short* oa = offattn + (size_t)qi * 384;

  // ---- owner geometry (level j) ----
  const int Wl = 128 >> j;
  const int W2 = Wl + 2;
  const int pst = (j == 0) ? 0 : (j == 1) ? 16900 : (j == 2) ? 21256 : 22412;
  const float fw = (float)Wl;

  // ---- distributed softmax: lane owns logits [4j, 4j+4) ----
  const uint2 lr = *(const uint2*)(oa + 256 + h * 16 + j * 4);
  const float l0 = bflo(lr.x), l1 = bfhi(lr.x);
  const float l2 = bflo(lr.y), l3 = bfhi(lr.y);
  float mx = fmaxf(fmaxf(l0, l1), fmaxf(l2, l3));
  mx = fmaxf(mx, swzf<0x041F>(mx));  // xor 1 (within quad)
  mx = fmaxf(mx, swzf<0x081F>(mx));  // xor 2
  const float e0v = __expf(l0 - mx), e1v = __expf(l1 - mx);
  const float e2v = __expf(l2 - mx), e3v = __expf(l3 - mx);
  float s = (e0v + e1v) + (e2v + e3v);
  s += swzf<0x041F>(s);
  s += swzf<0x081F>(s);
  const float inv = 1.f / s;
  const float aw4[4] = {e0v * inv, e1v * inv, e2v * inv, e3v * inv};

  const float2 rf = *(const float2*)(refpts + (size_t)qi * 8 + j * 2);
  const uint4 ov = *(const uint4*)(oa + h * 32 + j * 8);
  const unsigned op_[4] = {ov.x, ov.y, ov.z, ov.w};

  // ---- owner per-point math: 4 corner element-offsets + 4 weights --------
  unsigned eo[4][4];
  float wt[4][4];
#pragma unroll
  for (int pt = 0; pt < 4; ++pt) {
    const float ox = bflo(op_[pt]);
    const float oy = bfhi(op_[pt]);
    const float xs = fmaf(rf.x, fw, ox) - 0.5f;
    const float ys = fmaf(rf.y, fw, oy) - 0.5f;
    const float x0f = floorf(xs), y0f = floorf(ys);
    const float lx = xs - x0f, ly = ys - y0f;
    const int x0 = (int)x0f, y0 = (int)y0f;
    const float a = aw4[pt];
    const float wy1 = a * ly, wy0 = a - wy1;
    const float w01v = wy0 * lx, w00v = wy0 - w01v;
    const float w11v = wy1 * lx, w10v = wy1 - w11v;
    const int xb0 = min(max(x0 + 1, 0), Wl + 1);
    const int xb1 = min(max(x0 + 2, 0), Wl + 1);
    const int yb0 = min(max(y0 + 1, 0), Wl + 1);
    const int yb1 = min(max(y0 + 2, 0), Wl + 1);
    const unsigned r0 = (unsigned)(pst + yb0 * W2);
    const unsigned r1 = (unsigned)(pst + yb1 * W2);
    eo[pt][0] = (r0 + xb0) << 5;
    eo[pt][1] = (r0 + xb1) << 5;
    eo[pt][2] = (r1 + xb0) << 5;
    eo[pt][3] = (r1 + xb1) << 5;
    wt[pt][0] = w00v; wt[pt][1] = w01v; wt[pt][2] = w10v; wt[pt][3] = w11v;
  }

  const unsigned headbase =
      (unsigned)img * (PADCELLS * DDIM) + (unsigned)d0;

  f32x2 acc0 = (f32x2){0.f, 0.f}, acc1 = (f32x2){0.f, 0.f};
  f32x2 acc2 = (f32x2){0.f, 0.f}, acc3 = (f32x2){0.f, 0.f};

#define ACCUM(rv, wgt)                                 \
  {                                                    \
    f32x2 v_;                                          \
    v_.x = bflo(rv.x); v_.y = bfhi(rv.x);              \
    acc0 += v_ * (wgt);                                \
    v_.x = bflo(rv.y); v_.y = bfhi(rv.y);              \
    acc1 += v_ * (wgt);                                \
    v_.x = bflo(rv.z); v_.y = bfhi(rv.z);              \
    acc2 += v_ * (wgt);                                \
    v_.x = bflo(rv.w); v_.y = bfhi(rv.w);              \
    acc3 += v_ * (wgt);                                \
  }

// quad-broadcast from quad-lane LVL: and=0x1C, or=LVL, xor=0
#define POINT(LVL, PT)                                                  \
  {                                                                     \
    constexpr int IMM = (LVL << 5) | 0x1C;                              \
    const unsigned o00 = swzu<IMM>(eo[PT][0]);                          \
    const unsigned o01 = swzu<IMM>(eo[PT][1]);                          \
    const unsigned o10 = swzu<IMM>(eo[PT][2]);                          \
    const unsigned o11 = swzu<IMM>(eo[PT][3]);                          \
    const float w00 = swzf<IMM>(wt[PT][0]);                             \
    const float w01 = swzf<IMM>(wt[PT][1]);                             \
    const float w10 = swzf<IMM>(wt[PT][2]);                             \
    const float w11 = swzf<IMM>(wt[PT][3]);                             \
    const uint4 v00 = *(const uint4*)(vbf + headbase + o00);            \
    const uint4 v01 = *(const uint4*)(vbf + headbase + o01);            \
    const uint4 v10 = *(const uint4*)(vbf + headbase + o10);            \
    const uint4 v11 = *(const uint4*)(vbf + headbase + o11);            \
    ACCUM(v00, w00)                                                     \
    ACCUM(v01, w01)                                                     \
    ACCUM(v10, w10)                                                     \
    ACCUM(v11, w11)                                                     \
  }

  POINT(0, 0) POINT(0, 1) POINT(0, 2) POINT(0, 3)
  POINT(1, 0) POINT(1, 1) POINT(1, 2) POINT(1, 3)
  POINT(2, 0) POINT(2, 1) POINT(2, 2) POINT(2, 3)
  POINT(3, 0) POINT(3, 1) POINT(3, 2) POINT(3, 3)
#undef POINT
#undef ACCUM

  uint4 outv;
  outv.x = pk2bf(acc0.x, acc0.y);
  outv.y = pk2bf(acc1.x, acc1.y);
  outv.z = pk2bf(acc2.x, acc2.y);
  outv.w = pk2bf(acc3.x, acc3.y);
  *(uint4*)(msout + (size_t)qi * 256 + h * 32 + d0) = outv;
}

// ---------------- launch ----------------------------------------------------
extern "C" void kernel_launch(void* const* d_in, const int* in_sizes, int n_in,
                              void* d_out, int out_size, void* d_ws,
                              size_t ws_size, hipStream_t stream) {
  const float* query = (const float*)d_in[0];
  const float* refpts = (const float*)d_in[1];
  const float* value = (const float*)d_in[2];
  const float* W_off = (const float*)d_in[5];
  const float* b_off = (const float*)d_in[6];
  const float* W_attn = (const float*)d_in[7];
  const float* b_attn = (const float*)d_in[8];
  const float* W_val = (const float*)d_in[9];
  const float* b_val = (const float*)d_in[10];
  const float* W_out = (const float*)d_in[11];
  const float* b_out = (const float*)d_in[12];
  float* out = (float*)d_out;

  char* ws = (char*)d_ws;
  unsigned short* wtval = (unsigned short*)(ws);                 // 131072 B
  unsigned short* wtoa = (unsigned short*)(ws + 131072);         // 196608 B
  unsigned short* wtout = (unsigned short*)(ws + 327680);        // 131072 B
  unsigned short* vbf = (unsigned short*)(ws + 458752);          // 23281664 B
  unsigned short* offattn = (unsigned short*)(ws + 23740416);    // 33423360 B
  unsigned short* msout = (unsigned short*)(ws + 57163776);      // 22282240 B

  prep_zero_kernel<<<640, 256, 0, stream>>>(W_val, W_off, W_attn, W_out, wtval,
                                            wtoa, wtout, vbf);
  gemm01_kernel<<<1720, 256, 0, stream>>>(value, query, wtval, wtoa, b_val,
                                          b_off, b_attn, vbf, offattn);
  sampler_kernel<<<5440, 256, 0, stream>>>(vbf, offattn, refpts, msout);
  gemm2_kernel<<<688, 256, 0, stream>>>(msout, wtout, b_out, query, out);
}